// Round 1
// baseline (776.693 us; speedup 1.0000x reference)
//
#include <hip/hip_runtime.h>

#define RNN_B 4096
#define RNN_T 256
#define RNN_H 64   // hidden == input size

// 1 wave per batch row; lane j computes hidden unit j.
// Weights held in per-lane registers (lane j = rows j of W_ih / W_hh).
// x_t and h_{t-1} broadcast to all lanes via wave-private LDS rows.
__global__ __launch_bounds__(256, 2) void rnn_fused(
    const float* __restrict__ x,     // [B, T, 64]
    const float* __restrict__ h0,    // [1, B, 64]
    const float* __restrict__ Wih,   // [64, 64]
    const float* __restrict__ Whh,   // [64, 64]
    const float* __restrict__ bih,   // [64]
    const float* __restrict__ bhh,   // [64]
    float* __restrict__ out)         // [B*64 (hT)] then [B*T*64]
{
    const int w   = threadIdx.x >> 6;   // wave index in block (0..3)
    const int j   = threadIdx.x & 63;   // lane = hidden index
    const int row = (blockIdx.x << 2) + w;

    __shared__ float xs[4][64];
    __shared__ float hs[4][64];

    // Preload weight rows into registers (static indexing -> stays in VGPRs).
    float wih[64], whh[64];
#pragma unroll
    for (int i = 0; i < 64; i += 4) {
        *(float4*)(&wih[i]) = *(const float4*)(&Wih[j * 64 + i]);
        *(float4*)(&whh[i]) = *(const float4*)(&Whh[j * 64 + i]);
    }
    const float bias = bih[j] + bhh[j];

    float h = h0[row * 64 + j];
    hs[w][j] = h;

    const float* xp = x + (size_t)row * (RNN_T * 64) + j;
    float*       op = out + (size_t)RNN_B * 64 + (size_t)row * (RNN_T * 64) + j;

    float xv = xp[0];  // prefetch t=0
    for (int t = 0; t < RNN_T; ++t) {
        xs[w][j] = xv;                       // stage x_t row for broadcast
        if (t + 1 < RNN_T) xv = xp[(size_t)(t + 1) * 64];  // prefetch next

        float a0 = bias, a1 = 0.f, a2 = 0.f, a3 = 0.f;
#pragma unroll
        for (int i = 0; i < 64; i += 4) {    // input projection
            float4 xq = *(const float4*)(&xs[w][i]);   // broadcast ds_read_b128
            a0 += xq.x * wih[i + 0];
            a1 += xq.y * wih[i + 1];
            a2 += xq.z * wih[i + 2];
            a3 += xq.w * wih[i + 3];
        }
#pragma unroll
        for (int k = 0; k < 64; k += 4) {    // hidden projection
            float4 hq = *(const float4*)(&hs[w][k]);   // broadcast ds_read_b128
            a0 += hq.x * whh[k + 0];
            a1 += hq.y * whh[k + 1];
            a2 += hq.z * whh[k + 2];
            a3 += hq.w * whh[k + 3];
        }
        const float acc = (a0 + a1) + (a2 + a3);

        // tanh(a) = 1 - 2/(1 + e^{2a});  saturates correctly for large |a|
        const float e = __expf(2.0f * acc);
        h = 1.0f - 2.0f / (e + 1.0f);

        op[(size_t)t * 64] = h;              // coalesced 256B per wave
        hs[w][j] = h;                        // publish for next step (wave-private)
    }

    out[row * 64 + j] = h;                   // final hidden state
}

extern "C" void kernel_launch(void* const* d_in, const int* in_sizes, int n_in,
                              void* d_out, int out_size, void* d_ws, size_t ws_size,
                              hipStream_t stream) {
    const float* x   = (const float*)d_in[0];
    const float* h0  = (const float*)d_in[1];
    const float* Wih = (const float*)d_in[2];
    const float* Whh = (const float*)d_in[3];
    const float* bih = (const float*)d_in[4];
    const float* bhh = (const float*)d_in[5];
    float* out = (float*)d_out;

    dim3 grid(RNN_B / 4);   // 4 rows (waves) per block
    dim3 block(256);
    hipLaunchKernelGGL(rnn_fused, grid, block, 0, stream,
                       x, h0, Wih, Whh, bih, bhh, out);
}